// Round 3
// baseline (166.879 us; speedup 1.0000x reference)
//
#include <hip/hip_runtime.h>

#define NN 100000
#define NE 1250000
#define HD 64
#define BMW   3125     // bitmap words = NN/32
#define BMWPAD 3200    // padded for uint4 zeroing

#define CAP_L3   4096
#define CAP_L2   65536
#define CAP_L1   262144
#define CAP_NL2  4096
#define CAP_NL1  65536
#define CAP_NL0  262144

// ctrl indices: 0=cntL3 1=cntL2 2=cntL1 3=cntNL2 4=cntNL1 5=cntNL0 6=cntPL(=2)
// Bitmaps: B2 = NL2 membership, B1 = NL1, B0 = NL0 (may overlap).

__global__ void k_init(unsigned* B0, unsigned* B1, unsigned* B2,
                       float* cnt_in, int* ctrl, int* PL,
                       const int* __restrict__ pair) {
    int i = blockIdx.x * blockDim.x + threadIdx.x;
    if (i < BMWPAD / 4) {
        uint4 zz = make_uint4(0u, 0u, 0u, 0u);
        ((uint4*)B0)[i] = zz; ((uint4*)B1)[i] = zz; ((uint4*)B2)[i] = zz;
    }
    if (i < 16) ctrl[i] = (i == 6) ? 2 : 0;
    if (i == 0) {
        int p0 = pair[0], p1 = pair[1];
        PL[0] = p0; PL[1] = p1;
        cnt_in[p0] = 0.f; cnt_in[p1] = 0.f;
    }
}

// level-3 scan: edges into {pair} (direct compare, no gather); mark NL2 in B2
__global__ void k_scan3(const int* __restrict__ src, const int* __restrict__ dst,
                        const int* __restrict__ pair, unsigned* B2,
                        float* cnt_out, float* cnt_in,
                        int* L3, int* NL2, int* ctrl) {
    int t = blockIdx.x * blockDim.x + threadIdx.x;
    if (t >= NE / 4) return;
    int p0 = pair[0], p1 = pair[1];
    int4 d4 = ((const int4*)dst)[t];
#pragma unroll
    for (int k = 0; k < 4; ++k) {
        int d = (k == 0) ? d4.x : (k == 1) ? d4.y : (k == 2) ? d4.z : d4.w;
        if (d == p0 || d == p1) {
            int e = t * 4 + k, s = src[e];
            int idx = atomicAdd(&ctrl[0], 1);
            if (idx < CAP_L3) L3[idx] = e;
            unsigned m = 1u << (s & 31);
            unsigned old = atomicOr(&B2[s >> 5], m);
            if (!(old & m)) {
                cnt_out[s] = 0.f; cnt_in[s] = 0.f;
                int j = atomicAdd(&ctrl[3], 1);
                if (j < CAP_NL2) NL2[j] = s;
            }
        }
    }
}

// frontier scan with test-bitmap staged in LDS: collect edges whose dst bit is
// set in testbm; first-set src bit in setbm, zero its counters, append to NL.
__global__ __launch_bounds__(256) void k_scan_lds(
        const int* __restrict__ src, const int* __restrict__ dst,
        const unsigned* __restrict__ testbm, unsigned* setbm,
        float* cz_out, float* cz_in,
        int* L, int cntL_idx, int capL,
        int* NL, int cntNL_idx, int capNL, int* ctrl) {
    __shared__ unsigned bm[BMW];
    for (int i = threadIdx.x; i < BMW; i += blockDim.x) bm[i] = testbm[i];
    __syncthreads();
    const int nq = NE / 4;
    for (int t = blockIdx.x * blockDim.x + threadIdx.x; t < nq;
         t += gridDim.x * blockDim.x) {
        int4 d4 = ((const int4*)dst)[t];
#pragma unroll
        for (int k = 0; k < 4; ++k) {
            int d = (k == 0) ? d4.x : (k == 1) ? d4.y : (k == 2) ? d4.z : d4.w;
            if ((bm[d >> 5] >> (d & 31)) & 1u) {
                int e = t * 4 + k, s = src[e];
                int idx = atomicAdd(&ctrl[cntL_idx], 1);
                if (idx < capL) L[idx] = e;
                unsigned m = 1u << (s & 31);
                unsigned old = atomicOr(&setbm[s >> 5], m);
                if (!(old & m)) {
                    cz_out[s] = 0.f;
                    if (cz_in) cz_in[s] = 0.f;
                    int j = atomicAdd(&ctrl[cntNL_idx], 1);
                    if (j < capNL) NL[j] = s;
                }
            }
        }
    }
}

// out-degree for nodes in B0|B1|B2 (union OR'd into LDS)
__global__ __launch_bounds__(256) void k_degout(
        const int* __restrict__ src, const unsigned* __restrict__ B0,
        const unsigned* __restrict__ B1, const unsigned* __restrict__ B2,
        float* cnt_out) {
    __shared__ unsigned bm[BMW];
    for (int i = threadIdx.x; i < BMW; i += blockDim.x) bm[i] = B0[i] | B1[i] | B2[i];
    __syncthreads();
    const int nq = NE / 4;
    for (int t = blockIdx.x * blockDim.x + threadIdx.x; t < nq;
         t += gridDim.x * blockDim.x) {
        int4 s4 = ((const int4*)src)[t];
#pragma unroll
        for (int k = 0; k < 4; ++k) {
            int s = (k == 0) ? s4.x : (k == 1) ? s4.y : (k == 2) ? s4.z : s4.w;
            if ((bm[s >> 5] >> (s & 31)) & 1u) atomicAdd(&cnt_out[s], 1.0f);
        }
    }
}

// in-degrees from the collected edge lists (L* = exactly the in-edges of each frontier)
__global__ void k_cntin(const int* __restrict__ L3, const int* __restrict__ L2,
                        const int* __restrict__ L1, const int* __restrict__ ctrl,
                        const int* __restrict__ dst, float* cnt_in) {
    int c3 = min(ctrl[0], CAP_L3), c2 = min(ctrl[1], CAP_L2), c1 = min(ctrl[2], CAP_L1);
    int total = c3 + c2 + c1;
    for (int t = blockIdx.x * blockDim.x + threadIdx.x; t < total;
         t += gridDim.x * blockDim.x) {
        int e = (t < c3) ? L3[t] : (t < c3 + c2) ? L2[t - c3] : L1[t - c3 - c2];
        atomicAdd(&cnt_in[dst[e]], 1.0f);
    }
}

// x0 = z_table[z[v]] for NL0 nodes into bufA; zero NL1 rows of bufB (agg target)
__global__ void k_prep(const int* __restrict__ NL0, const int* __restrict__ NL1,
                       const int* __restrict__ ctrl, const int* __restrict__ z,
                       const float* __restrict__ zt, float* bufA, float* bufB) {
    int c0 = min(ctrl[5], CAP_NL0);
    int c1 = min(ctrl[4], CAP_NL1);
    int total = (c0 + c1) * HD;
    for (int t = blockIdx.x * blockDim.x + threadIdx.x; t < total;
         t += gridDim.x * blockDim.x) {
        int r = t >> 6, lane = t & 63;
        if (r < c0) { int v = NL0[r]; bufA[v * HD + lane] = zt[z[v] * HD + lane]; }
        else        { int v = NL1[r - c0]; bufB[v * HD + lane] = 0.0f; }
    }
}

__global__ void k_zero_rows(const int* __restrict__ NL, const int* __restrict__ ctrl,
                            int cnt_idx, int cap, float* buf) {
    int cnt = min(ctrl[cnt_idx], cap);
    int total = cnt * HD;
    for (int t = blockIdx.x * blockDim.x + threadIdx.x; t < total;
         t += gridDim.x * blockDim.x) {
        int v = NL[t >> 6];
        buf[v * HD + (t & 63)] = 0.0f;
    }
}

// agg[d] += (1/sqrt(max(out_deg,1)))[s] * xin[s] over collected edge list
__global__ void k_scatter(const int* __restrict__ L, const int* __restrict__ ctrl,
                          int cnt_idx, int cap,
                          const int* __restrict__ src, const int* __restrict__ dst,
                          const float* __restrict__ cnt_out,
                          const float* __restrict__ xin, float* agg) {
    int cnt = min(ctrl[cnt_idx], cap);
    int total = cnt * HD;
    for (int t = blockIdx.x * blockDim.x + threadIdx.x; t < total;
         t += gridDim.x * blockDim.x) {
        int e = L[t >> 6], lane = t & 63;
        int s = src[e], d = dst[e];
        float w = 1.0f / sqrtf(fmaxf(cnt_out[s], 1.0f));   // wave-uniform
        atomicAdd(&agg[d * HD + lane], w * xin[s * HD + lane]);
    }
}

// row-wise: buf[v] = (buf[v]*norm_in[v]) @ W + b  (optional relu), wave per row
__global__ __launch_bounds__(256) void k_gemm(const int* __restrict__ NL,
                                              const int* __restrict__ ctrl,
                                              int cnt_idx, int cap,
                                              const float* __restrict__ cnt_in,
                                              float* buf,
                                              const float* __restrict__ W,
                                              const float* __restrict__ bias,
                                              int do_relu) {
    int cnt = min(ctrl[cnt_idx], cap);
    int gtid = blockIdx.x * blockDim.x + threadIdx.x;
    int wave = gtid >> 6, lane = gtid & 63;
    int nw = (gridDim.x * blockDim.x) >> 6;
    float wb = bias[lane];
    for (int r = wave; r < cnt; r += nw) {
        int v = NL[r];
        float nin = 1.0f / sqrtf(fmaxf(cnt_in[v], 1.0f));
        float a = buf[v * HD + lane] * nin;
        float acc = wb;
#pragma unroll
        for (int i = 0; i < HD; ++i)
            acc += __shfl(a, i, 64) * W[i * HD + lane];
        buf[v * HD + lane] = do_relu ? fmaxf(acc, 0.0f) : acc;
    }
}

// h = x3[p0]*x3[p1]; t = relu(h@lin1+b1); out = t@lin2 + b2
__global__ void k_final(const float* __restrict__ bufB, const int* __restrict__ pair,
                        const float* __restrict__ l1w, const float* __restrict__ l1b,
                        const float* __restrict__ l2w, const float* __restrict__ l2b,
                        float* out) {
    int lane = threadIdx.x;  // 64 threads
    float h = bufB[pair[0] * HD + lane] * bufB[pair[1] * HD + lane];
    float t = l1b[lane];
#pragma unroll
    for (int i = 0; i < HD; ++i)
        t += __shfl(h, i, 64) * l1w[i * HD + lane];
    t = fmaxf(t, 0.0f);
    float val = t * l2w[lane];
#pragma unroll
    for (int off = 32; off; off >>= 1)
        val += __shfl_down(val, off, 64);
    if (lane == 0) out[0] = val + l2b[0];
}

extern "C" void kernel_launch(void* const* d_in, const int* in_sizes, int n_in,
                              void* d_out, int out_size, void* d_ws, size_t ws_size,
                              hipStream_t stream) {
    const int*   z    = (const int*)d_in[0];
    const int*   src  = (const int*)d_in[1];
    const int*   dst  = (const int*)d_in[2];
    const int*   pair = (const int*)d_in[3];
    const float* zt   = (const float*)d_in[4];
    const float* W1   = (const float*)d_in[5];
    const float* b1   = (const float*)d_in[6];
    const float* W2   = (const float*)d_in[7];
    const float* b2   = (const float*)d_in[8];
    const float* W3   = (const float*)d_in[9];
    const float* b3   = (const float*)d_in[10];
    const float* l1w  = (const float*)d_in[11];
    const float* l1b  = (const float*)d_in[12];
    const float* l2w  = (const float*)d_in[13];
    const float* l2b  = (const float*)d_in[14];
    float* out = (float*)d_out;

    char* w = (char*)d_ws;
    auto alloc = [&](size_t bytes) {
        char* p = w;
        w += (bytes + 255) & ~(size_t)255;
        return p;
    };
    float*    bufA    = (float*)alloc((size_t)NN * HD * 4);
    float*    bufB    = (float*)alloc((size_t)NN * HD * 4);
    float*    cnt_out = (float*)alloc((size_t)NN * 4);
    float*    cnt_in  = (float*)alloc((size_t)NN * 4);
    unsigned* B0      = (unsigned*)alloc((size_t)BMWPAD * 4);
    unsigned* B1      = (unsigned*)alloc((size_t)BMWPAD * 4);
    unsigned* B2      = (unsigned*)alloc((size_t)BMWPAD * 4);
    int*      L3      = (int*)alloc((size_t)CAP_L3 * 4);
    int*      L2      = (int*)alloc((size_t)CAP_L2 * 4);
    int*      L1      = (int*)alloc((size_t)CAP_L1 * 4);
    int*      NL2     = (int*)alloc((size_t)CAP_NL2 * 4);
    int*      NL1     = (int*)alloc((size_t)CAP_NL1 * 4);
    int*      NL0     = (int*)alloc((size_t)CAP_NL0 * 4);
    int*      PL      = (int*)alloc(256);
    int*      ctrl    = (int*)alloc(256);

    const int BN = 256;
    dim3 b(BN);
    dim3 gE4((NE / 4 + BN - 1) / BN);

    k_init<<<4, b, 0, stream>>>(B0, B1, B2, cnt_in, ctrl, PL, pair);
    k_scan3<<<gE4, b, 0, stream>>>(src, dst, pair, B2, cnt_out, cnt_in, L3, NL2, ctrl);
    k_scan_lds<<<512, b, 0, stream>>>(src, dst, B2, B1, cnt_out, cnt_in,
                                      L2, 1, CAP_L2, NL1, 4, CAP_NL1, ctrl);
    k_scan_lds<<<512, b, 0, stream>>>(src, dst, B1, B0, cnt_out, (float*)nullptr,
                                      L1, 2, CAP_L1, NL0, 5, CAP_NL0, ctrl);
    k_degout<<<512, b, 0, stream>>>(src, B0, B1, B2, cnt_out);
    k_cntin<<<32, b, 0, stream>>>(L3, L2, L1, ctrl, dst, cnt_in);
    k_prep<<<512, b, 0, stream>>>(NL0, NL1, ctrl, z, zt, bufA, bufB);

    // layer 1: bufA(x0) -> bufB(agg1) -> x1 in bufB
    k_scatter<<<512, b, 0, stream>>>(L1, ctrl, 2, CAP_L1, src, dst, cnt_out, bufA, bufB);
    k_gemm<<<256, b, 0, stream>>>(NL1, ctrl, 4, CAP_NL1, cnt_in, bufB, W1, b1, 1);

    // layer 2: bufB(x1) -> bufA(agg2) -> x2 in bufA
    k_zero_rows<<<64, b, 0, stream>>>(NL2, ctrl, 3, CAP_NL2, bufA);
    k_scatter<<<256, b, 0, stream>>>(L2, ctrl, 1, CAP_L2, src, dst, cnt_out, bufB, bufA);
    k_gemm<<<64, b, 0, stream>>>(NL2, ctrl, 3, CAP_NL2, cnt_in, bufA, W2, b2, 1);

    // layer 3: bufA(x2) -> bufB(agg3) -> x3 in bufB (no relu)
    k_zero_rows<<<1, b, 0, stream>>>(PL, ctrl, 6, 2, bufB);
    k_scatter<<<64, b, 0, stream>>>(L3, ctrl, 0, CAP_L3, src, dst, cnt_out, bufA, bufB);
    k_gemm<<<1, b, 0, stream>>>(PL, ctrl, 6, 2, cnt_in, bufB, W3, b3, 0);

    k_final<<<1, 64, 0, stream>>>(bufB, pair, l1w, l1b, l2w, l2b, out);
}